// Round 7
// baseline (339.679 us; speedup 1.0000x reference)
//
#include <hip/hip_runtime.h>

typedef unsigned short u16;
typedef __attribute__((ext_vector_type(8))) short bf16x8;
typedef __attribute__((ext_vector_type(8))) unsigned short u16x8;
typedef __attribute__((ext_vector_type(4))) float f32x4;
typedef __attribute__((ext_vector_type(4))) unsigned short u16x4;
typedef __attribute__((ext_vector_type(2))) unsigned int u32x2;
typedef __attribute__((ext_vector_type(4))) unsigned int u32x4;

#define Bn 8
#define Tn 4096
#define Cn 1024
#define HSn 128

#define SBAR __builtin_amdgcn_sched_barrier(0)

__device__ __forceinline__ float bf2f(u16 b) {
    unsigned u = ((unsigned)b) << 16;
    return __builtin_bit_cast(float, u);
}
// HW packed f32->bf16 (RNE), 1 VALU op for 2 values. No builtin on gfx950.
__device__ __forceinline__ unsigned cvt_pk_bf16(float a, float b) {
    unsigned r;
    asm("v_cvt_pk_bf16_f32 %0, %1, %2" : "=v"(r) : "v"(a), "v"(b));
    return r;
}
__device__ __forceinline__ u16 f2bf(float f) { return (u16)cvt_pk_bf16(f, f); }

// Workgroup barrier WITHOUT vmcnt drain: LDS visibility needs lgkmcnt(0) only.
__device__ __forceinline__ void wg_barrier() {
    __builtin_amdgcn_sched_barrier(0);
    asm volatile("s_waitcnt lgkmcnt(0)" ::: "memory");
    __builtin_amdgcn_s_barrier();
    __builtin_amdgcn_sched_barrier(0);
}

// global -> LDS direct DMA, 16B per lane (dwordx4). Dest is wave-uniform
// base + lane*16; global source IS per-lane (m173 pattern).
__device__ __forceinline__ void dma16(const void* g, void* l) {
    __builtin_amdgcn_global_load_lds(
        (const __attribute__((address_space(1))) unsigned int*)g,
        (__attribute__((address_space(3))) unsigned int*)l, 16, 0, 0);
}

// ---------------------------------------------------------------------------
// Kernel 1: W fp32 [k][n] (1024x128) -> Wt bf16 [n][k] (128x1024), x3.
// Softmax scale * log2(e) folded into Wq.
// ---------------------------------------------------------------------------
extern "C" __global__ __launch_bounds__(256) void head_wtrans(
    const float* __restrict__ Wq, const float* __restrict__ Wk,
    const float* __restrict__ Wv, u16* __restrict__ wt) {
    const float* W = (blockIdx.y == 0) ? Wq : (blockIdx.y == 1) ? Wk : Wv;
    const float scale =
        (blockIdx.y == 0) ? (0.08838834764831845f * 1.4426950408889634f) : 1.0f;
    u16* o = wt + (size_t)blockIdx.y * Cn * HSn;
    int tid = blockIdx.x * 256 + threadIdx.x;
    int n = tid >> 10, kk = tid & 1023;
    o[tid] = f2bf(W[kk * HSn + n] * scale);
}

// ---------------------------------------------------------------------------
// Kernel 2: FUSED QKV projection, round 7:
//   - x (HBM-bound): DMA depth-3 into 3 x 8KB LDS bufs (24 KB total ->
//     multi-block co-residency; r6 had 120KB -> 1 block/CU -> bare barriers).
//   - wt (L2-resident): NEVER staged; B fragments are lane-contiguous 16B
//     loads register-prefetched 1 step ahead (r4-verified layout).
//   - counted vmcnt(8) before each barrier; in-order retirement makes every
//     compiler B-reg wait retire the older x-DMA group -> never drains.
// 512 blocks x 256 thr (4 waves), BM=64, wave tile 64x96.
// ---------------------------------------------------------------------------
extern "C" __global__ __launch_bounds__(256) void head_proj(
    const float* __restrict__ x, const u16* __restrict__ wt, u16* __restrict__ qo,
    u16* __restrict__ ko, u16* __restrict__ vto) {
    __shared__ __align__(16) unsigned char sh[3 * 8192];  // 24 KB (epilogue tL overlays)
    const int tid = threadIdx.x;
    const int w = tid >> 6, l = tid & 63, quad = l >> 4, ln = l & 15;
    const int bm0 = blockIdx.x * 64;
    const int n0 = w * 96;

    const f32x4 zero4 = {0.f, 0.f, 0.f, 0.f};
    f32x4 acc[4][6];
#pragma unroll
    for (int fi = 0; fi < 4; fi++)
#pragma unroll
        for (int ci = 0; ci < 6; ci++) acc[fi][ci] = zero4;

    // x DMA sources (pre-swizzled 16B slots) + linear LDS dests
    const float* xg[2];
    int xd[2];
#pragma unroll
    for (int p = 0; p < 2; p++) {
        int s = p * 256 + tid;          // 512 slots of 16B = 8 KB
        int row = s >> 3, slot = s & 7;
        int g = slot ^ (row & 7);
        xg[p] = x + (size_t)(bm0 + row) * Cn + g * 4;
        xd[p] = s * 16;
    }
    // A-fragment LDS read offsets (same XOR)
    int aoff[4];
#pragma unroll
    for (int fi = 0; fi < 4; fi++) {
        int row = fi * 16 + ln;
        aoff[fi] = row * 128 + (((2 * quad) ^ (row & 7)) * 16);
    }
    // B pointers: 6 cols per lane, fragment = contiguous 16B at [col][k]
    const u16* bp[6];
#pragma unroll
    for (int ci = 0; ci < 6; ci++)
        bp[ci] = wt + (size_t)(n0 + ci * 16 + ln) * Cn + quad * 8;

#define P_DMA(BUF, KT)                                      \
    do {                                                    \
        dma16(xg[0] + (KT) * 32, sh + (BUF) * 8192 + xd[0]); \
        dma16(xg[1] + (KT) * 32, sh + (BUF) * 8192 + xd[1]); \
    } while (0)

#define P_LOADB(DST, KT)                                                  \
    do {                                                                  \
        _Pragma("unroll") for (int ci = 0; ci < 6; ci++)                  \
            DST[ci] = *(const u16x8*)(bp[ci] + (KT) * 32);                \
    } while (0)

#define P_COMPUTE(BUF, BREG)                                               \
    do {                                                                   \
        const unsigned char* cb = sh + (BUF) * 8192;                       \
        bf16x8 af[4];                                                      \
        _Pragma("unroll") for (int fi = 0; fi < 4; fi++) {                 \
            f32x4 lo = *(const f32x4*)(cb + aoff[fi]);                     \
            f32x4 hi = *(const f32x4*)(cb + (aoff[fi] ^ 16));              \
            u32x4 tt;                                                      \
            tt[0] = cvt_pk_bf16(lo[0], lo[1]);                             \
            tt[1] = cvt_pk_bf16(lo[2], lo[3]);                             \
            tt[2] = cvt_pk_bf16(hi[0], hi[1]);                             \
            tt[3] = cvt_pk_bf16(hi[2], hi[3]);                             \
            af[fi] = __builtin_bit_cast(bf16x8, tt);                       \
        }                                                                  \
        _Pragma("unroll") for (int ci = 0; ci < 6; ci++) {                 \
            bf16x8 bfr = __builtin_bit_cast(bf16x8, BREG[ci]);             \
            _Pragma("unroll") for (int fi = 0; fi < 4; fi++)               \
                acc[fi][ci] = __builtin_amdgcn_mfma_f32_16x16x32_bf16(     \
                    af[fi], bfr, acc[fi][ci], 0, 0, 0);                    \
        }                                                                  \
    } while (0)

#define P_BARRIER                                                  \
    do {                                                           \
        SBAR;                                                      \
        asm volatile("s_waitcnt vmcnt(8) lgkmcnt(0)" ::: "memory"); \
        __builtin_amdgcn_s_barrier();                              \
        SBAR;                                                      \
    } while (0)

    u16x8 bA[6], bB[6];
    // prologue: 3 DMA groups in flight, B(0) in regs; wait only for D(0).
    P_DMA(0, 0);
    P_DMA(1, 1);
    P_DMA(2, 2);
    P_LOADB(bA, 0);
    SBAR;
    asm volatile("s_waitcnt vmcnt(10)" ::: "memory");
    __builtin_amdgcn_s_barrier();
    SBAR;

    int c0 = 0;
    for (int t = 0; t < 32; t += 2) {
        int c1 = (c0 == 2) ? 0 : c0 + 1;
        if (t + 1 < 32) P_LOADB(bB, t + 1);
        P_COMPUTE(c0, bA);
        P_BARRIER;
        if (t + 3 < 32) P_DMA(c0, t + 3);
        if (t + 2 < 32) P_LOADB(bA, t + 2);
        P_COMPUTE(c1, bB);
        P_BARRIER;
        if (t + 4 < 32) P_DMA(c1, t + 4);
        c0 = (c1 == 2) ? 0 : c1 + 1;
    }
#undef P_DMA
#undef P_LOADB
#undef P_COMPUTE
#undef P_BARRIER

    // ---- epilogue: q/k direct; v -> LDS transpose -> coalesced stores ----
    u16* const tL = (u16*)sh;  // [128 d][80] u16 = 20480 B (bufs dead)
#pragma unroll
    for (int ci = 0; ci < 6; ci++) {
        int col = n0 + ci * 16 + ln;
        int cin = col & 127;
        int sidx = col >> 7;  // wave-uniform per ci
#pragma unroll
        for (int fi = 0; fi < 4; fi++) {
            int grow = bm0 + fi * 16 + quad * 4;
            if (sidx == 0) {
#pragma unroll
                for (int r = 0; r < 4; r++)
                    qo[(size_t)(grow + r) * HSn + cin] = f2bf(acc[fi][ci][r]);
            } else if (sidx == 1) {
#pragma unroll
                for (int r = 0; r < 4; r++)
                    ko[(size_t)(grow + r) * HSn + cin] = f2bf(acc[fi][ci][r]);
            } else {
                u16x4 pk4;
#pragma unroll
                for (int r = 0; r < 4; r++) pk4[r] = f2bf(acc[fi][ci][r]);
                *(u16x4*)(tL + cin * 80 + (fi * 16 + quad * 4)) = pk4;
            }
        }
    }
    wg_barrier();
    {
        const int bb = bm0 >> 12, t0b = bm0 & 4095;
        const int dl = tid >> 3, tch = (tid & 7) * 8;  // 32 d rows x 64 t per pass
#pragma unroll
        for (int dp = 0; dp < 4; dp++) {
            int d = dp * 32 + dl;
            u16x8 vv = *(const u16x8*)(tL + d * 80 + tch);
            *(u16x8*)(vto + ((size_t)bb * HSn + d) * Tn + t0b + tch) = vv;
        }
    }
}

// ===========================================================================
// Kernel 3a: flash chunk, QBLK=256, fixed 16-tile K-chunks:
//   - 512 blocks (16 qbi x 8 b x 4 c), big bands dispatched first.
//   - chunk c covers tiles [tlo+16c, min(tlo+16c+15, thi)]; short bands
//     early-exit (combine recomputes chunk count from geometry).
//   - 8 waves x 32 q-rows (2 groups of 16); kL/vL reads shared across the
//     two groups (halves LDS read traffic per MFMA).
//   - static max (m=0), wave-private pL, 2 lgkm-only barriers/tile.
// LDS 72704 B. Partials: Opart[cid][256][128] bf16, lsum[cid][256] fp32.
// ---------------------------------------------------------------------------
extern "C" __global__ __launch_bounds__(512) void head_flash_chunk(
    const u16* __restrict__ q, const u16* __restrict__ k, const u16* __restrict__ vt,
    u16* __restrict__ Opart, float* __restrict__ lsum) {
    __shared__ __align__(16) u16 kL[64 * 136];   // 17408 B
    __shared__ __align__(16) u16 vL[128 * 72];   // 18432 B
    __shared__ __align__(16) u16 pL[8 * 32 * 72]; // 36864 B
    const int tid = threadIdx.x;
    const int w = tid >> 6, l = tid & 63, quad = l >> 4, ln = l & 15;
    const int cid = blockIdx.x;
    const int grp = cid >> 5;          // 0..15
    const int qbi = 15 - grp;          // big bands first
    const int b = (cid >> 2) & 7;
    const int c = cid & 3;

    const int q0 = qbi * 256;
    const int qmax = q0 + 255;
    const int tlo = (2047 - (qmax >> 1)) >> 6;
    const int thi = (2047 + ((qmax + 1) >> 1)) >> 6;
    const int kstart = tlo + c * 16;
    if (kstart > thi) return;  // short band: chunk empty (combine skips it)
    const int kend = (kstart + 15 < thi) ? (kstart + 15) : thi;

    const int qrow = q0 + w * 32;

    const int rkBase = tid >> 4, ckK = tid & 15;  // 32 rows x 16 chunks
    const int rvBase = tid >> 3, ckV = tid & 7;   // 64 rows x 8 chunks

    bf16x8 qf[2][4];
#pragma unroll
    for (int g = 0; g < 2; g++)
#pragma unroll
        for (int ks = 0; ks < 4; ks++)
            qf[g][ks] = *(const bf16x8*)(q + ((size_t)b * Tn + qrow + g * 16 + ln) * HSn +
                                         ks * 32 + quad * 8);

    const f32x4 zero4 = {0.f, 0.f, 0.f, 0.f};
    float l2[2] = {0.f, 0.f};
    int clo[2], chi[2];
#pragma unroll
    for (int g = 0; g < 2; g++) {
        int qme = qrow + g * 16 + ln;
        clo[g] = 2047 - (qme >> 1);
        chi[g] = 2047 + ((qme + 1) >> 1);
    }
    const int cloW0 = 2047 - (qrow >> 1);
    const int chiW0 = 2047 + ((qrow + 1) >> 1);
    const int cloMin = 2047 - ((qrow + 31) >> 1);
    const int chiMax = 2047 + ((qrow + 32) >> 1);
    f32x4 o[2][8];
#pragma unroll
    for (int g = 0; g < 2; g++)
#pragma unroll
        for (int dt = 0; dt < 8; dt++) o[g][dt] = zero4;

    u16x8 pk[2], pv[2];
    {
        const int t0 = kstart * 64;
#pragma unroll
        for (int p = 0; p < 2; p++)
            pk[p] = *(const u16x8*)(k + ((size_t)b * Tn + t0 + p * 32 + rkBase) * HSn +
                                    ckK * 8);
#pragma unroll
        for (int p = 0; p < 2; p++)
            pv[p] = *(const u16x8*)(vt + ((size_t)b * HSn + p * 64 + rvBase) * Tn + t0 +
                                    ckV * 8);
    }

    for (int kt = kstart; kt <= kend; kt++) {
        const int t0 = kt * 64;
        wg_barrier();  // B1: prior tile's kL/vL reads complete everywhere
#pragma unroll
        for (int p = 0; p < 2; p++)
            *(u16x8*)(kL + (p * 32 + rkBase) * 136 + ckK * 8) = pk[p];
#pragma unroll
        for (int p = 0; p < 2; p++)
            *(u16x8*)(vL + (p * 64 + rvBase) * 72 + ckV * 8) = pv[p];
        if (kt < kend) {
            const int t1 = t0 + 64;
#pragma unroll
            for (int p = 0; p < 2; p++)
                pk[p] = *(const u16x8*)(k + ((size_t)b * Tn + t1 + p * 32 + rkBase) * HSn +
                                        ckK * 8);
#pragma unroll
            for (int p = 0; p < 2; p++)
                pv[p] = *(const u16x8*)(vt + ((size_t)b * HSn + p * 64 + rvBase) * Tn +
                                        t1 + ckV * 8);
        }
        wg_barrier();  // B2: staging visible (prefetch vmcnt NOT drained)

        const bool live = !((t0 + 63 < cloMin) || (t0 > chiMax));

        if (live) {
            f32x4 s[2][4];
#pragma unroll
            for (int g = 0; g < 2; g++)
#pragma unroll
                for (int nt = 0; nt < 4; nt++) s[g][nt] = zero4;
            __builtin_amdgcn_s_setprio(1);
#pragma unroll
            for (int nt = 0; nt < 4; nt++) {
                int R = nt * 16 + ln;
#pragma unroll
                for (int ks = 0; ks < 4; ks++) {
                    bf16x8 kf = *(const bf16x8*)(kL + R * 136 + (ks * 4 + quad) * 8);
                    s[0][nt] =
                        __builtin_amdgcn_mfma_f32_16x16x32_bf16(kf, qf[0][ks], s[0][nt], 0, 0, 0);
                    s[1][nt] =
                        __builtin_amdgcn_mfma_f32_16x16x32_bf16(kf, qf[1][ks], s[1][nt], 0, 0, 0);
                }
            }
            __builtin_amdgcn_s_setprio(0);
            if (t0 < cloW0 || t0 + 63 > chiW0) {
#pragma unroll
                for (int g = 0; g < 2; g++)
#pragma unroll
                    for (int nt = 0; nt < 4; nt++)
#pragma unroll
                        for (int r = 0; r < 4; r++) {
                            int t = t0 + nt * 16 + quad * 4 + r;
                            bool valid = (t >= clo[g]) && (t <= chi[g]);
                            s[g][nt][r] = valid ? s[g][nt][r] : -1e30f;
                        }
            }
#pragma unroll
            for (int g = 0; g < 2; g++) {
                float ls = 0.f;
#pragma unroll
                for (int nt = 0; nt < 4; nt++) {
                    float p0 = exp2f(s[g][nt][0]), p1 = exp2f(s[g][nt][1]);
                    float p2 = exp2f(s[g][nt][2]), p3 = exp2f(s[g][nt][3]);
                    ls += (p0 + p1) + (p2 + p3);
                    u32x2 d;
                    d.x = cvt_pk_bf16(p0, p1);
                    d.y = cvt_pk_bf16(p2, p3);
                    *(u32x2*)(pL + w * 2304 + g * 1152 + ln * 72 + nt * 16 + quad * 4) = d;
                }
                l2[g] += ls;
            }
            __builtin_amdgcn_s_setprio(1);
#pragma unroll
            for (int jt = 0; jt < 2; jt++) {
                bf16x8 pf0 = *(const bf16x8*)(pL + w * 2304 + ln * 72 + jt * 32 + quad * 8);
                bf16x8 pf1 =
                    *(const bf16x8*)(pL + w * 2304 + 1152 + ln * 72 + jt * 32 + quad * 8);
#pragma unroll
                for (int dt = 0; dt < 8; dt++) {
                    int R = dt * 16 + ln;
                    bf16x8 vf = *(const bf16x8*)(vL + R * 72 + (jt * 4 + quad) * 8);
                    o[0][dt] = __builtin_amdgcn_mfma_f32_16x16x32_bf16(pf0, vf, o[0][dt], 0, 0, 0);
                    o[1][dt] = __builtin_amdgcn_mfma_f32_16x16x32_bf16(pf1, vf, o[1][dt], 0, 0, 0);
                }
            }
            __builtin_amdgcn_s_setprio(0);
        }
    }
#pragma unroll
    for (int g = 0; g < 2; g++) {
        l2[g] += __shfl_xor(l2[g], 16, 64);
        l2[g] += __shfl_xor(l2[g], 32, 64);
    }
#pragma unroll
    for (int g = 0; g < 2; g++)
#pragma unroll
        for (int dt = 0; dt < 8; dt++)
#pragma unroll
            for (int r = 0; r < 4; r++)
                Opart[((size_t)cid * 256 + w * 32 + g * 16 + quad * 4 + r) * HSn +
                      dt * 16 + ln] = f2bf(o[g][dt][r]);
    if (l < 16) {
#pragma unroll
        for (int g = 0; g < 2; g++)
            lsum[(size_t)cid * 256 + w * 32 + g * 16 + ln] = l2[g];
    }
}

// ---------------------------------------------------------------------------
// Kernel 3b: combine up to 4 chunks per (b,qbi): out = sum O_c / sum l_c.
// Chunk count nc recomputed from band geometry; empty chunks never read.
// 512 blocks x 256 threads; each block 64 rows x 128 cols.
// ---------------------------------------------------------------------------
extern "C" __global__ __launch_bounds__(256) void head_combine(
    const u16* __restrict__ Opart, const float* __restrict__ lsum,
    float* __restrict__ out) {
    const int bid = blockIdx.x;
    const int qb64 = bid >> 3, b = bid & 7;
    const int tid = threadIdx.x;
    const int row = tid >> 2, dseg = (tid & 3) * 32;
    const int gq = qb64 * 64 + row;
    const int qbi = gq >> 8, inrow = gq & 255;
    const int qmax = qbi * 256 + 255;
    const int tlo = (2047 - (qmax >> 1)) >> 6;
    const int thi = (2047 + ((qmax + 1) >> 1)) >> 6;
    const int nc = (thi - tlo + 16) >> 4;  // ceil(W/16), 1..4
    const int cid0 = (15 - qbi) * 32 + b * 4;

    float accv[32];
#pragma unroll
    for (int e = 0; e < 32; e++) accv[e] = 0.f;
    float lt = 0.f;
    for (int cc = 0; cc < nc; cc++) {
        size_t base = (size_t)(cid0 + cc) * 256 + inrow;
        lt += lsum[base];
        const u16* p = Opart + base * HSn + dseg;
#pragma unroll
        for (int j = 0; j < 4; j++) {
            u16x8 a = *(const u16x8*)(p + j * 8);
#pragma unroll
            for (int e = 0; e < 8; e++) accv[j * 8 + e] += bf2f(a[e]);
        }
    }
    float inv = 1.0f / lt;
    float* op = out + ((size_t)b * Tn + gq) * HSn + dseg;
#pragma unroll
    for (int j = 0; j < 8; j++) {
        f32x4 o1;
#pragma unroll
        for (int e = 0; e < 4; e++) o1[e] = accv[j * 4 + e] * inv;
        *(f32x4*)(op + j * 4) = o1;
    }
}

// ---------------------------------------------------------------------------
// Kernel 3-mono (fallback when ws too small for partials): round-5 flash.
// ---------------------------------------------------------------------------
extern "C" __global__ __launch_bounds__(256) void head_flash(
    const u16* __restrict__ q, const u16* __restrict__ k, const u16* __restrict__ vt,
    float* __restrict__ out) {
    __shared__ __align__(16) u16 kL[64 * 136];
    __shared__ __align__(16) u16 vL[128 * 72];
    __shared__ __align__(16) u16 pL[4 * 16 * 72];
    const int tid = threadIdx.x;
    const int w = tid >> 6, l = tid & 63, quad = l >> 4, ln = l & 15;
    const int bx = blockIdx.x;
    const int half = bx >> 8, idx = bx & 255;
    const int p5 = idx & 31, b = idx >> 5;
    const int qb = half ? p5 : 63 - p5;
    const int q0 = qb * 64;
    const int qrow = q0 + w * 16;
    const int rkBase = tid >> 4, ckK = tid & 15;
    const int rvBase = tid >> 3, ckV = tid & 7;

    bf16x8 qf[4];
#pragma unroll
    for (int ks = 0; ks < 4; ks++)
        qf[ks] = *(const bf16x8*)(q + ((size_t)b * Tn + qrow + ln) * HSn + ks * 32 +
                                  quad * 8);
    const f32x4 zero4 = {0.f, 0.f, 0.f, 0.f};
    float m2 = -1e30f, l2 = 0.f;
    const int qme = qrow + ln;
    const int clo = 2047 - (qme >> 1), chi = 2047 + ((qme + 1) >> 1);
    f32x4 o[8];
#pragma unroll
    for (int dt = 0; dt < 8; dt++) o[dt] = zero4;
    const int qmax = q0 + 63;
    const int tlo = (2047 - (qmax >> 1)) >> 6;
    const int thi = (2047 + ((qmax + 1) >> 1)) >> 6;

    u16x8 pk[4], pv[4];
    {
        const int t0 = tlo * 64;
#pragma unroll
        for (int p = 0; p < 4; p++)
            pk[p] = *(const u16x8*)(k + ((size_t)b * Tn + t0 + p * 16 + rkBase) * HSn +
                                    ckK * 8);
#pragma unroll
        for (int p = 0; p < 4; p++)
            pv[p] = *(const u16x8*)(vt + ((size_t)b * HSn + p * 32 + rvBase) * Tn + t0 +
                                    ckV * 8);
    }
    for (int kt = tlo; kt <= thi; kt++) {
        const int t0 = kt * 64;
        __syncthreads();
#pragma unroll
        for (int p = 0; p < 4; p++)
            *(u16x8*)(kL + (p * 16 + rkBase) * 136 + ckK * 8) = pk[p];
#pragma unroll
        for (int p = 0; p < 4; p++)
            *(u16x8*)(vL + (p * 32 + rvBase) * 72 + ckV * 8) = pv[p];
        if (kt < thi) {
            const int t1 = t0 + 64;
#pragma unroll
            for (int p = 0; p < 4; p++)
                pk[p] = *(const u16x8*)(k + ((size_t)b * Tn + t1 + p * 16 + rkBase) * HSn +
                                        ckK * 8);
#pragma unroll
            for (int p = 0; p < 4; p++)
                pv[p] = *(const u16x8*)(vt + ((size_t)b * HSn + p * 32 + rvBase) * Tn +
                                        t1 + ckV * 8);
        }
        __syncthreads();
        f32x4 s[4];
#pragma unroll
        for (int nt = 0; nt < 4; nt++) s[nt] = zero4;
#pragma unroll
        for (int nt = 0; nt < 4; nt++) {
            int R = nt * 16 + ln;
#pragma unroll
            for (int ks = 0; ks < 4; ks++) {
                bf16x8 kf = *(const bf16x8*)(kL + R * 136 + (ks * 4 + quad) * 8);
                s[nt] = __builtin_amdgcn_mfma_f32_16x16x32_bf16(kf, qf[ks], s[nt], 0, 0, 0);
            }
        }
#pragma unroll
        for (int nt = 0; nt < 4; nt++)
#pragma unroll
            for (int r = 0; r < 4; r++) {
                int t = t0 + nt * 16 + quad * 4 + r;
                bool valid = (t >= clo) && (t <= chi);
                s[nt][r] = valid ? s[nt][r] : -1e30f;
            }
        float mc = s[0][0];
#pragma unroll
        for (int nt = 0; nt < 4; nt++)
#pragma unroll
            for (int r = 0; r < 4; r++) mc = fmaxf(mc, s[nt][r]);
        mc = fmaxf(mc, __shfl_xor(mc, 16, 64));
        mc = fmaxf(mc, __shfl_xor(mc, 32, 64));
        float mn = fmaxf(m2, mc);
        float alpha = exp2f(m2 - mn);
        m2 = mn;
        float ls = 0.f;
#pragma unroll
        for (int nt = 0; nt < 4; nt++) {
            float p0 = exp2f(s[nt][0] - mn), p1 = exp2f(s[nt][1] - mn);
            float p2 = exp2f(s[nt][2] - mn), p3 = exp2f(s[nt][3] - mn);
            ls += (p0 + p1) + (p2 + p3);
            u32x2 d;
            d.x = cvt_pk_bf16(p0, p1);
            d.y = cvt_pk_bf16(p2, p3);
            *(u32x2*)(pL + w * 1152 + ln * 72 + nt * 16 + quad * 4) = d;
        }
        ls += __shfl_xor(ls, 16, 64);
        ls += __shfl_xor(ls, 32, 64);
        l2 = l2 * alpha + ls;
        float aR[4];
#pragma unroll
        for (int r = 0; r < 4; r++) aR[r] = __shfl(alpha, quad * 4 + r, 64);
#pragma unroll
        for (int dt = 0; dt < 8; dt++) {
            f32x4 oo = o[dt];
#pragma unroll
            for (int r = 0; r < 4; r++) oo[r] *= aR[r];
            o[dt] = oo;
        }
#pragma unroll
        for (int jt = 0; jt < 2; jt++) {
            bf16x8 pf = *(const bf16x8*)(pL + w * 1152 + ln * 72 + jt * 32 + quad * 8);
#pragma unroll
            for (int dt = 0; dt < 8; dt++) {
                int R = dt * 16 + ln;
                bf16x8 vf = *(const bf16x8*)(vL + R * 72 + (jt * 4 + quad) * 8);
                o[dt] = __builtin_amdgcn_mfma_f32_16x16x32_bf16(pf, vf, o[dt], 0, 0, 0);
            }
        }
    }
    float inv = 1.0f / l2;
    float rl[4];
#pragma unroll
    for (int r = 0; r < 4; r++) rl[r] = __shfl(inv, quad * 4 + r, 64);
#pragma unroll
    for (int dt = 0; dt < 8; dt++)
#pragma unroll
        for (int r = 0; r < 4; r++) {
            int row = qrow + quad * 4 + r;
            out[((size_t)b * Tn + row) * HSn + dt * 16 + ln] = o[dt][r] * rl[r];
        }
}

// ---------------------------------------------------------------------------
extern "C" void kernel_launch(void* const* d_in, const int* in_sizes, int n_in,
                              void* d_out, int out_size, void* d_ws, size_t ws_size,
                              hipStream_t stream) {
    const float* x = (const float*)d_in[0];
    const float* Wq = (const float*)d_in[1];
    const float* Wk = (const float*)d_in[2];
    const float* Wv = (const float*)d_in[3];
    float* outp = (float*)d_out;
    char* ws = (char*)d_ws;
    // ws: wt @0 (768KB), q @1MB, k @9MB, vt @17MB (8MB each),
    // Opart bf16 @25MB (32MB), lsum fp32 @58MB (512KB) -> needs ~59MB.
    u16* wt = (u16*)(ws);
    u16* qb = (u16*)(ws + (1u << 20));
    u16* kb = (u16*)(ws + (9u << 20));
    u16* vtb = (u16*)(ws + (17u << 20));
    u16* Opart = (u16*)(ws + (25u << 20));
    float* lsum = (float*)(ws + (58u << 20));

    head_wtrans<<<dim3(512, 3), 256, 0, stream>>>(Wq, Wk, Wv, wt);
    head_proj<<<dim3(512), 256, 0, stream>>>(x, wt, qb, kb, vtb);
    if (ws_size >= (60ull << 20)) {
        head_flash_chunk<<<dim3(512), 512, 0, stream>>>(qb, kb, vtb, Opart, lsum);
        head_combine<<<dim3(512), 256, 0, stream>>>(Opart, lsum, outp);
    } else {
        head_flash<<<dim3(512), 256, 0, stream>>>(qb, kb, vtb, outp);
    }
}

// Round 8
// 310.466 us; speedup vs baseline: 1.0941x; 1.0941x over previous
//
#include <hip/hip_runtime.h>

typedef unsigned short u16;
typedef __attribute__((ext_vector_type(8))) short bf16x8;
typedef __attribute__((ext_vector_type(8))) unsigned short u16x8;
typedef __attribute__((ext_vector_type(4))) float f32x4;
typedef __attribute__((ext_vector_type(4))) unsigned short u16x4;
typedef __attribute__((ext_vector_type(2))) unsigned int u32x2;
typedef __attribute__((ext_vector_type(4))) unsigned int u32x4;

#define Bn 8
#define Tn 4096
#define Cn 1024
#define HSn 128

#define SBAR __builtin_amdgcn_sched_barrier(0)

__device__ __forceinline__ float bf2f(u16 b) {
    unsigned u = ((unsigned)b) << 16;
    return __builtin_bit_cast(float, u);
}
// HW packed f32->bf16 (RNE), 1 VALU op for 2 values. No builtin on gfx950.
__device__ __forceinline__ unsigned cvt_pk_bf16(float a, float b) {
    unsigned r;
    asm("v_cvt_pk_bf16_f32 %0, %1, %2" : "=v"(r) : "v"(a), "v"(b));
    return r;
}
__device__ __forceinline__ u16 f2bf(float f) { return (u16)cvt_pk_bf16(f, f); }

// Workgroup barrier WITHOUT vmcnt drain: LDS visibility needs lgkmcnt(0) only.
__device__ __forceinline__ void wg_barrier() {
    __builtin_amdgcn_sched_barrier(0);
    asm volatile("s_waitcnt lgkmcnt(0)" ::: "memory");
    __builtin_amdgcn_s_barrier();
    __builtin_amdgcn_sched_barrier(0);
}

// global -> LDS direct DMA, 16B per lane (dwordx4). Dest is wave-uniform
// base + lane*16; global source IS per-lane (m173 pattern).
__device__ __forceinline__ void dma16(const void* g, void* l) {
    __builtin_amdgcn_global_load_lds(
        (const __attribute__((address_space(1))) unsigned int*)g,
        (__attribute__((address_space(3))) unsigned int*)l, 16, 0, 0);
}

// ---------------------------------------------------------------------------
// Kernel 1: W fp32 [k][n] (1024x128) -> Wt bf16 [n][k] (128x1024), x3.
// Softmax scale * log2(e) folded into Wq.
// ---------------------------------------------------------------------------
extern "C" __global__ __launch_bounds__(256) void head_wtrans(
    const float* __restrict__ Wq, const float* __restrict__ Wk,
    const float* __restrict__ Wv, u16* __restrict__ wt) {
    const float* W = (blockIdx.y == 0) ? Wq : (blockIdx.y == 1) ? Wk : Wv;
    const float scale =
        (blockIdx.y == 0) ? (0.08838834764831845f * 1.4426950408889634f) : 1.0f;
    u16* o = wt + (size_t)blockIdx.y * Cn * HSn;
    int tid = blockIdx.x * 256 + threadIdx.x;
    int n = tid >> 10, kk = tid & 1023;
    o[tid] = f2bf(W[kk * HSn + n] * scale);
}

// ---------------------------------------------------------------------------
// Kernel 2: FUSED QKV projection, round 8: decoupled dual-depth pipeline.
//   - x: DMA depth-3 into 3 x 8KB LDS bufs (24 KB).
//   - wt: register prefetch DEPTH-2 (rotating b0/b1/b2, static indices).
//   - Issue order per phase: compute(t); barrier; B(t+2); DMA(t+3);
//     vmcnt(16) [= retire exactly D(t+1), ~2.5 phases old]; barrier.
//     r7 bug: B(t+1) issued after D(t+2) forced D(t+2) retirement 1 phase
//     early (in-order vmcnt) -> effective DMA depth 1. Now every wait
//     targets loads >= 2 phases old.
// 512 blocks x 256 thr (4 waves), BM=64, wave tile 64x96.
// ---------------------------------------------------------------------------
extern "C" __global__ __launch_bounds__(256) void head_proj(
    const float* __restrict__ x, const u16* __restrict__ wt, u16* __restrict__ qo,
    u16* __restrict__ ko, u16* __restrict__ vto) {
    __shared__ __align__(16) unsigned char sh[3 * 8192];  // 24 KB (epilogue tL overlays)
    const int tid = threadIdx.x;
    const int w = tid >> 6, l = tid & 63, quad = l >> 4, ln = l & 15;
    const int bm0 = blockIdx.x * 64;
    const int n0 = w * 96;

    const f32x4 zero4 = {0.f, 0.f, 0.f, 0.f};
    f32x4 acc[4][6];
#pragma unroll
    for (int fi = 0; fi < 4; fi++)
#pragma unroll
        for (int ci = 0; ci < 6; ci++) acc[fi][ci] = zero4;

    // x DMA sources (pre-swizzled 16B slots) + linear LDS dests
    const float* xg[2];
    int xd[2];
#pragma unroll
    for (int p = 0; p < 2; p++) {
        int s = p * 256 + tid;          // 512 slots of 16B = 8 KB
        int row = s >> 3, slot = s & 7;
        int g = slot ^ (row & 7);
        xg[p] = x + (size_t)(bm0 + row) * Cn + g * 4;
        xd[p] = s * 16;
    }
    // A-fragment LDS read offsets (same XOR)
    int aoff[4];
#pragma unroll
    for (int fi = 0; fi < 4; fi++) {
        int row = fi * 16 + ln;
        aoff[fi] = row * 128 + (((2 * quad) ^ (row & 7)) * 16);
    }
    // B pointers: 6 cols per lane, fragment = contiguous 16B at [col][k]
    const u16* bp[6];
#pragma unroll
    for (int ci = 0; ci < 6; ci++)
        bp[ci] = wt + (size_t)(n0 + ci * 16 + ln) * Cn + quad * 8;

#define P_DMA(BUF, KT)                                       \
    do {                                                     \
        dma16(xg[0] + (KT) * 32, sh + (BUF) * 8192 + xd[0]); \
        dma16(xg[1] + (KT) * 32, sh + (BUF) * 8192 + xd[1]); \
    } while (0)

#define P_LOADB(DST, KT)                                   \
    do {                                                   \
        _Pragma("unroll") for (int ci = 0; ci < 6; ci++)   \
            DST[ci] = *(const u16x8*)(bp[ci] + (KT) * 32); \
    } while (0)

#define P_COMPUTE(BUF, BREG)                                               \
    do {                                                                   \
        const unsigned char* cb = sh + (BUF) * 8192;                       \
        bf16x8 af[4];                                                      \
        _Pragma("unroll") for (int fi = 0; fi < 4; fi++) {                 \
            f32x4 lo = *(const f32x4*)(cb + aoff[fi]);                     \
            f32x4 hi = *(const f32x4*)(cb + (aoff[fi] ^ 16));              \
            u32x4 tt;                                                      \
            tt[0] = cvt_pk_bf16(lo[0], lo[1]);                             \
            tt[1] = cvt_pk_bf16(lo[2], lo[3]);                             \
            tt[2] = cvt_pk_bf16(hi[0], hi[1]);                             \
            tt[3] = cvt_pk_bf16(hi[2], hi[3]);                             \
            af[fi] = __builtin_bit_cast(bf16x8, tt);                       \
        }                                                                  \
        _Pragma("unroll") for (int ci = 0; ci < 6; ci++) {                 \
            bf16x8 bfr = __builtin_bit_cast(bf16x8, BREG[ci]);             \
            _Pragma("unroll") for (int fi = 0; fi < 4; fi++)               \
                acc[fi][ci] = __builtin_amdgcn_mfma_f32_16x16x32_bf16(     \
                    af[fi], bfr, acc[fi][ci], 0, 0, 0);                    \
        }                                                                  \
    } while (0)

// one pipeline phase at time T using LDS buf BUF and B-set BCUR; prefetches
// B(T+2) into BNXT and refills BUF with x(T+3).
#define P_PHASE(T, BUF, BCUR, BNXT)                                         \
    do {                                                                    \
        int t_ = (T);                                                       \
        if (t_ < 32) {                                                      \
            P_COMPUTE(BUF, BCUR);                                           \
            wg_barrier();                                                   \
            if (t_ + 2 < 32) P_LOADB(BNXT, t_ + 2);                         \
            if (t_ + 3 < 32) P_DMA(BUF, t_ + 3);                            \
            SBAR;                                                           \
            if (t_ <= 28)                                                   \
                asm volatile("s_waitcnt vmcnt(16)" ::: "memory");           \
            else if (t_ == 29)                                              \
                asm volatile("s_waitcnt vmcnt(14)" ::: "memory");           \
            else if (t_ == 30)                                              \
                asm volatile("s_waitcnt vmcnt(6)" ::: "memory");            \
            if (t_ < 31) __builtin_amdgcn_s_barrier();                      \
            SBAR;                                                           \
        }                                                                   \
    } while (0)

    u16x8 b0[6], b1[6], b2[6];
    // prologue: D0,B0,D1,B1,D2 (B before younger DMA -> minimal coupling).
    P_DMA(0, 0);
    P_LOADB(b0, 0);
    P_DMA(1, 1);
    P_LOADB(b1, 1);
    P_DMA(2, 2);
    SBAR;
    asm volatile("s_waitcnt vmcnt(16)" ::: "memory");  // D0 done (queue=18)
    __builtin_amdgcn_s_barrier();
    SBAR;

    for (int t3 = 0; t3 < 33; t3 += 3) {
        P_PHASE(t3 + 0, 0, b0, b2);
        P_PHASE(t3 + 1, 1, b1, b0);
        P_PHASE(t3 + 2, 2, b2, b1);
    }
#undef P_DMA
#undef P_LOADB
#undef P_COMPUTE
#undef P_PHASE

    // ---- epilogue: q/k direct; v -> LDS transpose -> coalesced stores ----
    u16* const tL = (u16*)sh;  // [128 d][80] u16 = 20480 B (bufs dead)
#pragma unroll
    for (int ci = 0; ci < 6; ci++) {
        int col = n0 + ci * 16 + ln;
        int cin = col & 127;
        int sidx = col >> 7;  // wave-uniform per ci
#pragma unroll
        for (int fi = 0; fi < 4; fi++) {
            int grow = bm0 + fi * 16 + quad * 4;
            if (sidx == 0) {
#pragma unroll
                for (int r = 0; r < 4; r++)
                    qo[(size_t)(grow + r) * HSn + cin] = f2bf(acc[fi][ci][r]);
            } else if (sidx == 1) {
#pragma unroll
                for (int r = 0; r < 4; r++)
                    ko[(size_t)(grow + r) * HSn + cin] = f2bf(acc[fi][ci][r]);
            } else {
                u16x4 pk4;
#pragma unroll
                for (int r = 0; r < 4; r++) pk4[r] = f2bf(acc[fi][ci][r]);
                *(u16x4*)(tL + cin * 80 + (fi * 16 + quad * 4)) = pk4;
            }
        }
    }
    wg_barrier();
    {
        const int bb = bm0 >> 12, t0b = bm0 & 4095;
        const int dl = tid >> 3, tch = (tid & 7) * 8;  // 32 d rows x 64 t per pass
#pragma unroll
        for (int dp = 0; dp < 4; dp++) {
            int d = dp * 32 + dl;
            u16x8 vv = *(const u16x8*)(tL + d * 80 + tch);
            *(u16x8*)(vto + ((size_t)bb * HSn + d) * Tn + t0b + tch) = vv;
        }
    }
}

// ===========================================================================
// Kernel 3a: split-K flash chunk, QBLK=128 (reverted to round-6 version;
// QBLK=256 regressed 48->103 us via makespan + occupancy loss):
//   - 8 waves / 512 threads, 512 blocks (32 qbi x 8 b x 2 halves).
//   - static max (m=0), wave-private pL, 2 lgkm-only barriers/tile.
// LDS 54272 B -> 3 blocks/CU.
// ---------------------------------------------------------------------------
extern "C" __global__ __launch_bounds__(512) void head_flash_chunk(
    const u16* __restrict__ q, const u16* __restrict__ k, const u16* __restrict__ vt,
    u16* __restrict__ Opart, float* __restrict__ lsum) {
    __shared__ __align__(16) u16 kL[64 * 136];    // 17408 B
    __shared__ __align__(16) u16 vL[128 * 72];    // 18432 B
    __shared__ __align__(16) u16 pL[8 * 16 * 72]; // 18432 B
    const int tid = threadIdx.x;
    const int w = tid >> 6, l = tid & 63, quad = l >> 4, ln = l & 15;
    const int cid = blockIdx.x;
    const int grp = cid >> 4;  // 0..31
    const int qbi = (grp < 16) ? (31 - grp) : (grp - 16);
    const int b = (cid >> 1) & 7;
    const int half = cid & 1;
    const int q0 = qbi * 128;
    const int qrow = q0 + w * 16;

    const int rkBase = tid >> 4, ckK = tid & 15;  // 32 rows x 16 chunks
    const int rvBase = tid >> 3, ckV = tid & 7;   // 64 rows x 8 chunks

    bf16x8 qf[4];
#pragma unroll
    for (int ks = 0; ks < 4; ks++)
        qf[ks] = *(const bf16x8*)(q + ((size_t)b * Tn + qrow + ln) * HSn + ks * 32 +
                                  quad * 8);

    const f32x4 zero4 = {0.f, 0.f, 0.f, 0.f};
    float l2 = 0.f;
    const int qme = qrow + ln;
    const int clo = 2047 - (qme >> 1), chi = 2047 + ((qme + 1) >> 1);
    const int cloW0 = 2047 - (qrow >> 1);
    const int chiW0 = 2047 + ((qrow + 1) >> 1);
    const int cloMin = 2047 - ((qrow + 15) >> 1);
    const int chiMax = 2047 + ((qrow + 16) >> 1);
    f32x4 o[8];
#pragma unroll
    for (int dt = 0; dt < 8; dt++) o[dt] = zero4;

    const int qmax = q0 + 127;
    const int tlo = (2047 - (qmax >> 1)) >> 6;
    const int thi = (2047 + ((qmax + 1) >> 1)) >> 6;
    const int W = thi - tlo + 1;
    const int c0 = (W + 1) >> 1;
    const int kstart = half ? tlo + c0 : tlo;
    const int kend = half ? thi : tlo + c0 - 1;

    u16x8 pk[2], pv[2];
    {
        const int t0 = kstart * 64;
#pragma unroll
        for (int p = 0; p < 2; p++)
            pk[p] = *(const u16x8*)(k + ((size_t)b * Tn + t0 + p * 32 + rkBase) * HSn +
                                    ckK * 8);
#pragma unroll
        for (int p = 0; p < 2; p++)
            pv[p] = *(const u16x8*)(vt + ((size_t)b * HSn + p * 64 + rvBase) * Tn + t0 +
                                    ckV * 8);
    }

    for (int kt = kstart; kt <= kend; kt++) {
        const int t0 = kt * 64;
        wg_barrier();  // B1: prior tile's kL/vL reads complete everywhere
#pragma unroll
        for (int p = 0; p < 2; p++)
            *(u16x8*)(kL + (p * 32 + rkBase) * 136 + ckK * 8) = pk[p];
#pragma unroll
        for (int p = 0; p < 2; p++)
            *(u16x8*)(vL + (p * 64 + rvBase) * 72 + ckV * 8) = pv[p];
        if (kt < kend) {
            const int t1 = t0 + 64;
#pragma unroll
            for (int p = 0; p < 2; p++)
                pk[p] = *(const u16x8*)(k + ((size_t)b * Tn + t1 + p * 32 + rkBase) * HSn +
                                        ckK * 8);
#pragma unroll
            for (int p = 0; p < 2; p++)
                pv[p] = *(const u16x8*)(vt + ((size_t)b * HSn + p * 64 + rvBase) * Tn +
                                        t1 + ckV * 8);
        }
        wg_barrier();  // B2: staging visible (prefetch vmcnt NOT drained)

        const bool live = !((t0 + 63 < cloMin) || (t0 > chiMax));

        if (live) {
            f32x4 s[4];
#pragma unroll
            for (int nt = 0; nt < 4; nt++) s[nt] = zero4;
            __builtin_amdgcn_s_setprio(1);
#pragma unroll
            for (int nt = 0; nt < 4; nt++) {
                int R = nt * 16 + ln;
#pragma unroll
                for (int ks = 0; ks < 4; ks++) {
                    bf16x8 kf = *(const bf16x8*)(kL + R * 136 + (ks * 4 + quad) * 8);
                    s[nt] =
                        __builtin_amdgcn_mfma_f32_16x16x32_bf16(kf, qf[ks], s[nt], 0, 0, 0);
                }
            }
            __builtin_amdgcn_s_setprio(0);
            if (t0 < cloW0 || t0 + 63 > chiW0) {
#pragma unroll
                for (int nt = 0; nt < 4; nt++)
#pragma unroll
                    for (int r = 0; r < 4; r++) {
                        int t = t0 + nt * 16 + quad * 4 + r;
                        bool valid = (t >= clo) && (t <= chi);
                        s[nt][r] = valid ? s[nt][r] : -1e30f;
                    }
            }
            float ls = 0.f;
#pragma unroll
            for (int nt = 0; nt < 4; nt++) {
                float p0 = exp2f(s[nt][0]), p1 = exp2f(s[nt][1]);
                float p2 = exp2f(s[nt][2]), p3 = exp2f(s[nt][3]);
                ls += (p0 + p1) + (p2 + p3);
                u32x2 d;
                d.x = cvt_pk_bf16(p0, p1);
                d.y = cvt_pk_bf16(p2, p3);
                *(u32x2*)(pL + w * 1152 + ln * 72 + nt * 16 + quad * 4) = d;
            }
            l2 += ls;
            __builtin_amdgcn_s_setprio(1);
#pragma unroll
            for (int jt = 0; jt < 2; jt++) {
                bf16x8 pf = *(const bf16x8*)(pL + w * 1152 + ln * 72 + jt * 32 + quad * 8);
#pragma unroll
                for (int dt = 0; dt < 8; dt++) {
                    int R = dt * 16 + ln;
                    bf16x8 vf = *(const bf16x8*)(vL + R * 72 + (jt * 4 + quad) * 8);
                    o[dt] = __builtin_amdgcn_mfma_f32_16x16x32_bf16(pf, vf, o[dt], 0, 0, 0);
                }
            }
            __builtin_amdgcn_s_setprio(0);
        }
    }
    l2 += __shfl_xor(l2, 16, 64);
    l2 += __shfl_xor(l2, 32, 64);
#pragma unroll
    for (int dt = 0; dt < 8; dt++)
#pragma unroll
        for (int r = 0; r < 4; r++)
            Opart[((size_t)cid * 128 + w * 16 + quad * 4 + r) * HSn + dt * 16 + ln] =
                f2bf(o[dt][r]);
    if (l < 16) lsum[(size_t)cid * 128 + w * 16 + ln] = l2;
}

// ---------------------------------------------------------------------------
// Kernel 3b: combine 2 chunks per (b,qbi): out = (O0 + O1) / (l0 + l1).
// 512 blocks x 256 threads; each block does 64 rows x 128 cols.
// ---------------------------------------------------------------------------
extern "C" __global__ __launch_bounds__(256) void head_combine(
    const u16* __restrict__ Opart, const float* __restrict__ lsum,
    float* __restrict__ out) {
    const int bid = blockIdx.x;
    const int qb64 = bid >> 3, b = bid & 7;  // 64-row group 0..63
    const int tid = threadIdx.x;
    const int row = tid >> 2, dseg = (tid & 3) * 32;
    const int qbi = qb64 >> 1;
    const int inrow = (qb64 & 1) * 64 + row;  // row within 128-row chunk
    const int grp0 = (qbi >= 16) ? (31 - qbi) : (qbi + 16);
    const int cid0 = grp0 * 16 + b * 2;
    const size_t r0 = (size_t)cid0 * 128 + inrow, r1 = r0 + 128;
    float l0 = lsum[r0], l1 = lsum[r1];
    float inv = 1.0f / (l0 + l1);
    float* op = out + ((size_t)b * Tn + qb64 * 64 + row) * HSn + dseg;
    const u16* p0 = Opart + r0 * HSn + dseg;
    const u16* p1 = Opart + r1 * HSn + dseg;
#pragma unroll
    for (int j = 0; j < 4; j++) {
        u16x8 a = *(const u16x8*)(p0 + j * 8);
        u16x8 c = *(const u16x8*)(p1 + j * 8);
        f32x4 o1, o2;
#pragma unroll
        for (int e = 0; e < 4; e++) o1[e] = (bf2f(a[e]) + bf2f(c[e])) * inv;
#pragma unroll
        for (int e = 0; e < 4; e++) o2[e] = (bf2f(a[4 + e]) + bf2f(c[4 + e])) * inv;
        *(f32x4*)(op + j * 8) = o1;
        *(f32x4*)(op + j * 8 + 4) = o2;
    }
}

// ---------------------------------------------------------------------------
// Kernel 3-mono (fallback when ws too small for partials): round-5 flash.
// ---------------------------------------------------------------------------
extern "C" __global__ __launch_bounds__(256) void head_flash(
    const u16* __restrict__ q, const u16* __restrict__ k, const u16* __restrict__ vt,
    float* __restrict__ out) {
    __shared__ __align__(16) u16 kL[64 * 136];
    __shared__ __align__(16) u16 vL[128 * 72];
    __shared__ __align__(16) u16 pL[4 * 16 * 72];
    const int tid = threadIdx.x;
    const int w = tid >> 6, l = tid & 63, quad = l >> 4, ln = l & 15;
    const int bx = blockIdx.x;
    const int half = bx >> 8, idx = bx & 255;
    const int p5 = idx & 31, b = idx >> 5;
    const int qb = half ? p5 : 63 - p5;
    const int q0 = qb * 64;
    const int qrow = q0 + w * 16;
    const int rkBase = tid >> 4, ckK = tid & 15;
    const int rvBase = tid >> 3, ckV = tid & 7;

    bf16x8 qf[4];
#pragma unroll
    for (int ks = 0; ks < 4; ks++)
        qf[ks] = *(const bf16x8*)(q + ((size_t)b * Tn + qrow + ln) * HSn + ks * 32 +
                                  quad * 8);
    const f32x4 zero4 = {0.f, 0.f, 0.f, 0.f};
    float m2 = -1e30f, l2 = 0.f;
    const int qme = qrow + ln;
    const int clo = 2047 - (qme >> 1), chi = 2047 + ((qme + 1) >> 1);
    f32x4 o[8];
#pragma unroll
    for (int dt = 0; dt < 8; dt++) o[dt] = zero4;
    const int qmax = q0 + 63;
    const int tlo = (2047 - (qmax >> 1)) >> 6;
    const int thi = (2047 + ((qmax + 1) >> 1)) >> 6;

    u16x8 pk[4], pv[4];
    {
        const int t0 = tlo * 64;
#pragma unroll
        for (int p = 0; p < 4; p++)
            pk[p] = *(const u16x8*)(k + ((size_t)b * Tn + t0 + p * 16 + rkBase) * HSn +
                                    ckK * 8);
#pragma unroll
        for (int p = 0; p < 4; p++)
            pv[p] = *(const u16x8*)(vt + ((size_t)b * HSn + p * 32 + rvBase) * Tn + t0 +
                                    ckV * 8);
    }
    for (int kt = tlo; kt <= thi; kt++) {
        const int t0 = kt * 64;
        __syncthreads();
#pragma unroll
        for (int p = 0; p < 4; p++)
            *(u16x8*)(kL + (p * 16 + rkBase) * 136 + ckK * 8) = pk[p];
#pragma unroll
        for (int p = 0; p < 4; p++)
            *(u16x8*)(vL + (p * 32 + rvBase) * 72 + ckV * 8) = pv[p];
        if (kt < thi) {
            const int t1 = t0 + 64;
#pragma unroll
            for (int p = 0; p < 4; p++)
                pk[p] = *(const u16x8*)(k + ((size_t)b * Tn + t1 + p * 16 + rkBase) * HSn +
                                        ckK * 8);
#pragma unroll
            for (int p = 0; p < 4; p++)
                pv[p] = *(const u16x8*)(vt + ((size_t)b * HSn + p * 32 + rvBase) * Tn +
                                        t1 + ckV * 8);
        }
        __syncthreads();
        f32x4 s[4];
#pragma unroll
        for (int nt = 0; nt < 4; nt++) s[nt] = zero4;
#pragma unroll
        for (int nt = 0; nt < 4; nt++) {
            int R = nt * 16 + ln;
#pragma unroll
            for (int ks = 0; ks < 4; ks++) {
                bf16x8 kf = *(const bf16x8*)(kL + R * 136 + (ks * 4 + quad) * 8);
                s[nt] = __builtin_amdgcn_mfma_f32_16x16x32_bf16(kf, qf[ks], s[nt], 0, 0, 0);
            }
        }
#pragma unroll
        for (int nt = 0; nt < 4; nt++)
#pragma unroll
            for (int r = 0; r < 4; r++) {
                int t = t0 + nt * 16 + quad * 4 + r;
                bool valid = (t >= clo) && (t <= chi);
                s[nt][r] = valid ? s[nt][r] : -1e30f;
            }
        float mc = s[0][0];
#pragma unroll
        for (int nt = 0; nt < 4; nt++)
#pragma unroll
            for (int r = 0; r < 4; r++) mc = fmaxf(mc, s[nt][r]);
        mc = fmaxf(mc, __shfl_xor(mc, 16, 64));
        mc = fmaxf(mc, __shfl_xor(mc, 32, 64));
        float mn = fmaxf(m2, mc);
        float alpha = exp2f(m2 - mn);
        m2 = mn;
        float ls = 0.f;
#pragma unroll
        for (int nt = 0; nt < 4; nt++) {
            float p0 = exp2f(s[nt][0] - mn), p1 = exp2f(s[nt][1] - mn);
            float p2 = exp2f(s[nt][2] - mn), p3 = exp2f(s[nt][3] - mn);
            ls += (p0 + p1) + (p2 + p3);
            u32x2 d;
            d.x = cvt_pk_bf16(p0, p1);
            d.y = cvt_pk_bf16(p2, p3);
            *(u32x2*)(pL + w * 1152 + ln * 72 + nt * 16 + quad * 4) = d;
        }
        ls += __shfl_xor(ls, 16, 64);
        ls += __shfl_xor(ls, 32, 64);
        l2 = l2 * alpha + ls;
        float aR[4];
#pragma unroll
        for (int r = 0; r < 4; r++) aR[r] = __shfl(alpha, quad * 4 + r, 64);
#pragma unroll
        for (int dt = 0; dt < 8; dt++) {
            f32x4 oo = o[dt];
#pragma unroll
            for (int r = 0; r < 4; r++) oo[r] *= aR[r];
            o[dt] = oo;
        }
#pragma unroll
        for (int jt = 0; jt < 2; jt++) {
            bf16x8 pf = *(const bf16x8*)(pL + w * 1152 + ln * 72 + jt * 32 + quad * 8);
#pragma unroll
            for (int dt = 0; dt < 8; dt++) {
                int R = dt * 16 + ln;
                bf16x8 vf = *(const bf16x8*)(vL + R * 72 + (jt * 4 + quad) * 8);
                o[dt] = __builtin_amdgcn_mfma_f32_16x16x32_bf16(pf, vf, o[dt], 0, 0, 0);
            }
        }
    }
    float inv = 1.0f / l2;
    float rl[4];
#pragma unroll
    for (int r = 0; r < 4; r++) rl[r] = __shfl(inv, quad * 4 + r, 64);
#pragma unroll
    for (int dt = 0; dt < 8; dt++)
#pragma unroll
        for (int r = 0; r < 4; r++) {
            int row = qrow + quad * 4 + r;
            out[((size_t)b * Tn + row) * HSn + dt * 16 + ln] = o[dt][r] * rl[r];
        }
}

// ---------------------------------------------------------------------------
extern "C" void kernel_launch(void* const* d_in, const int* in_sizes, int n_in,
                              void* d_out, int out_size, void* d_ws, size_t ws_size,
                              hipStream_t stream) {
    const float* x = (const float*)d_in[0];
    const float* Wq = (const float*)d_in[1];
    const float* Wk = (const float*)d_in[2];
    const float* Wv = (const float*)d_in[3];
    float* outp = (float*)d_out;
    char* ws = (char*)d_ws;
    // ws: wt @0 (768KB), q @1MB, k @9MB, vt @17MB (8MB each),
    // Opart bf16 @25MB (16.78MB), lsum fp32 @42MB (256KB) -> needs ~43MB.
    u16* wt = (u16*)(ws);
    u16* qb = (u16*)(ws + (1u << 20));
    u16* kb = (u16*)(ws + (9u << 20));
    u16* vtb = (u16*)(ws + (17u << 20));
    u16* Opart = (u16*)(ws + (25u << 20));
    float* lsum = (float*)(ws + (42u << 20));

    head_wtrans<<<dim3(512, 3), 256, 0, stream>>>(Wq, Wk, Wv, wt);
    head_proj<<<dim3(512), 256, 0, stream>>>(x, wt, qb, kb, vtb);
    if (ws_size >= (44ull << 20)) {
        head_flash_chunk<<<dim3(512), 512, 0, stream>>>(qb, kb, vtb, Opart, lsum);
        head_combine<<<dim3(512), 256, 0, stream>>>(Opart, lsum, outp);
    } else {
        head_flash<<<dim3(512), 256, 0, stream>>>(qb, kb, vtb, outp);
    }
}